// Round 2
// 689.293 us; speedup vs baseline: 1.0140x; 1.0140x over previous
//
#include <hip/hip_runtime.h>
#include <stdint.h>

// Problem constants (fixed by reference: x_in (32, 4096, 512) fp32)
#define T_LEN 4096
#define C_LEN 512
#define B_LEN 32
#define W_LEN 2055           // floor((T + 16 - 1)/2)
#define W_PITCH 2064         // padded: rows 64B-aligned (2064*4 = 8256 = 129*64)
#define ROWS (B_LEN * C_LEN) // 16384

typedef float f32x4 __attribute__((ext_vector_type(4))); // for nontemporal st

// db8 decomposition low-pass filter (float32-rounded)
__device__ __constant__ float c_dec_lo[16] = {
    (float)-0.00011747678400228192, (float)0.0006754494059985568,
    (float)-0.0003917403729959771,  (float)-0.00487035299301066,
    (float)0.008746094047015655,    (float)0.013981027917015516,
    (float)-0.04408825393106472,    (float)-0.01736930100202211,
    (float)0.128747426620186,       (float)0.00047248457399797254,
    (float)-0.2840155429624281,     (float)-0.015829105256023893,
    (float)0.5853546836548691,      (float)0.6756307362980128,
    (float)0.3128715909144659,      (float)0.05441584224308161};

// Symmetric extension: E[j] -> x index. E = [x14..x0 | x0..x_{T-1} | x_{T-1}..]
__device__ __forceinline__ int sym_idx(int j) {
  int t = j - 15;
  if (t < 0) t = -1 - t;
  if (t >= T_LEN) t = 2 * T_LEN - 1 - t;
  return t;
}

// ---------------------------------------------------------------------------
// K1: DWT. low[n] = sum_u DEC_LO[u] * E[2n+16-u]; DEC_HI[u]=(u odd?+:-)DEC_LO[15-u]
// Block: 256 thr, (b, 64-channel tile, 64-w tile). Register-window stencil:
// each thread loads its 46-wide E window once (was 128 scalar LDS reads with
// 4.3x redundancy), computes 16 w's. W_T=64 cuts x halo re-read 1.24x->1.11x
// and doubles store segments to 256 B.
// ---------------------------------------------------------------------------
#define K1_WT 64
#define K1_JEXT (2 * K1_WT + 14) // 142
#define K1_PITCH 68              // float4-aligned staging pitch
#define K1_TPITCH 67             // transpose pitch: (3c+w)%32 -> <=2-way (free)

__global__ __launch_bounds__(256) void k_dwt(const float* __restrict__ x,
                                             float* __restrict__ lo,
                                             float* __restrict__ hi) {
  __shared__ float lds[K1_JEXT * K1_PITCH]; // 38624 B; reused as 64x67 stage
  const int w0 = blockIdx.x * K1_WT;
  const int bc = blockIdx.y;
  const int b = bc >> 3;
  const int c0 = (bc & 7) * 64;
  const int tid = threadIdx.x;
  const int jlo = 2 * w0 + 1;

  // Phase 1: stage E tile [142 j][64 c] with float4 loads (coalesced along c)
  for (int r = tid; r < K1_JEXT * 16; r += 256) {
    int jj = r >> 4;
    int c4 = (r & 15) * 4;
    int t = sym_idx(jlo + jj);
    float4 v = *(const float4*)(x + ((size_t)b * T_LEN + t) * C_LEN + c0 + c4);
    *(float4*)&lds[jj * K1_PITCH + c4] = v;
  }
  __syncthreads();

  // Phase 2: each thread computes 16 w's for one channel via register window
  const int c = tid & 63;
  const int wq = tid >> 6; // 0..3 (16 w's each)
  float E[46];
#pragma unroll
  for (int i = 0; i < 46; ++i) E[i] = lds[(32 * wq + i) * K1_PITCH + c];
  float rlo[16], rhi[16];
#pragma unroll
  for (int k = 0; k < 16; ++k) {
    float accl = 0.f, acch = 0.f;
#pragma unroll
    for (int u = 0; u < 16; ++u) {
      float e = E[2 * k + 15 - u]; // == staged E[2*wi+15-u], wi = wq*16+k
      float dl = c_dec_lo[u];
      float dh = (u & 1) ? c_dec_lo[15 - u] : -c_dec_lo[15 - u];
      accl = fmaf(dl, e, accl);
      acch = fmaf(dh, e, acch);
    }
    rlo[k] = accl;
    rhi[k] = acch;
  }

  // Phase 3: transpose through LDS (pitch 67), float4 256B-segment stores
  const int wlim = W_LEN - w0; // <64 only on last tile
  float* st = lds;             // alias: phase-2 E reads finished before sync
  for (int pass = 0; pass < 2; ++pass) {
    __syncthreads();
#pragma unroll
    for (int k = 0; k < 16; ++k)
      st[c * K1_TPITCH + wq * 16 + k] = pass ? rhi[k] : rlo[k];
    __syncthreads();
    float* dst = pass ? hi : lo;
    for (int r = tid; r < 64 * 16; r += 256) {
      int cc = r >> 4;
      int w4 = (r & 15) * 4;
      size_t base = (size_t)(b * C_LEN + c0 + cc) * W_PITCH + w0 + w4;
      if (w4 + 3 < wlim) {
        float4 v = {st[cc * K1_TPITCH + w4], st[cc * K1_TPITCH + w4 + 1],
                    st[cc * K1_TPITCH + w4 + 2], st[cc * K1_TPITCH + w4 + 3]};
        *(float4*)(dst + base) = v;
      } else {
#pragma unroll
        for (int i = 0; i < 4; ++i)
          if (w4 + i < wlim) dst[base + i] = st[cc * K1_TPITCH + w4 + i];
      }
    }
  }
}

// ---------------------------------------------------------------------------
// K2: per-row quantile via 3-pass radix select (11/11/10-bit digits) on float
// bit patterns (squares >=0 so uint order == float order). Block per row.
// Pass-0 histogram is fused into the staging loop (saves one 2055-key pass).
// Histogram stored swizzled: bin -> (bin&7)*256 + (bin>>3) so the scan's
// 8-bins-per-thread reads are conflict-free. Wave scans via shfl.
// ---------------------------------------------------------------------------
__global__ __launch_bounds__(256) void k_thresh(const float* __restrict__ hi,
                                                const float* __restrict__ qp,
                                                float* __restrict__ thr) {
  __shared__ uint32_t keys[2056];
  __shared__ uint32_t hist[2048];
  __shared__ uint32_t s_wsum[4];
  __shared__ int s_bin, s_kk, s_cnt;
  __shared__ uint32_t s_minv;
  const int row = blockIdx.x;
  const int tid = threadIdx.x;
  const int lane = tid & 63;
  const int wv = tid >> 6;

  const float q = qp[0];
  float pos = __fmul_rn(q, (float)(W_LEN - 1));
  if (pos < 0.f) pos = 0.f;
  if (pos > (float)(W_LEN - 1)) pos = (float)(W_LEN - 1);
  const int lo_i = (int)floorf(pos);
  const int hi_i = (int)ceilf(pos);
  const float gw = pos - floorf(pos);
  const float lw = 1.0f - gw;

  // zero pass-0 histogram, then stage squared keys + accumulate pass-0 digits
  for (int r = tid; r < 2048; r += 256) hist[r] = 0;
  __syncthreads();
  const float* rowp = hi + (size_t)row * W_PITCH;
  for (int r = tid; r < 513; r += 256) { // 513*4 = 2052
    float4 v = *(const float4*)(rowp + r * 4);
    uint32_t k0 = __float_as_uint(__fmul_rn(v.x, v.x));
    uint32_t k1 = __float_as_uint(__fmul_rn(v.y, v.y));
    uint32_t k2 = __float_as_uint(__fmul_rn(v.z, v.z));
    uint32_t k3 = __float_as_uint(__fmul_rn(v.w, v.w));
    keys[r * 4 + 0] = k0;
    keys[r * 4 + 1] = k1;
    keys[r * 4 + 2] = k2;
    keys[r * 4 + 3] = k3;
    uint32_t d;
    d = (k0 >> 21) & 0x7FFu;
    atomicAdd(&hist[((d & 7) << 8) + (d >> 3)], 1u);
    d = (k1 >> 21) & 0x7FFu;
    atomicAdd(&hist[((d & 7) << 8) + (d >> 3)], 1u);
    d = (k2 >> 21) & 0x7FFu;
    atomicAdd(&hist[((d & 7) << 8) + (d >> 3)], 1u);
    d = (k3 >> 21) & 0x7FFu;
    atomicAdd(&hist[((d & 7) << 8) + (d >> 3)], 1u);
  }
  if (tid < 3) {
    float h = rowp[2052 + tid];
    uint32_t k0 = __float_as_uint(__fmul_rn(h, h));
    keys[2052 + tid] = k0;
    uint32_t d = (k0 >> 21) & 0x7FFu;
    atomicAdd(&hist[((d & 7) << 8) + (d >> 3)], 1u);
  }

  int kk = lo_i;
  uint32_t pref = 0;
  const int shifts[3] = {21, 10, 0};
  const uint32_t cmask[3] = {0u, 0xFFE00000u, 0xFFFFFC00u};
  const uint32_t dmask[3] = {0x7FFu, 0x7FFu, 0x3FFu};

#pragma unroll
  for (int p = 0; p < 3; ++p) {
    const int shift = shifts[p];
    if (p > 0) {
      __syncthreads();
      for (int r = tid; r < 2048; r += 256) hist[r] = 0;
      __syncthreads();
      for (int r = tid; r < W_LEN; r += 256) {
        uint32_t key = keys[r];
        if ((key & cmask[p]) == (pref & cmask[p])) {
          uint32_t d = (key >> shift) & dmask[p];
          atomicAdd(&hist[((d & 7) << 8) + (d >> 3)], 1u);
        }
      }
    }
    __syncthreads();
    // scan: each thread owns 8 consecutive bins
    uint32_t c8[8];
    uint32_t sum8 = 0;
#pragma unroll
    for (int i = 0; i < 8; ++i) {
      c8[i] = hist[i * 256 + tid];
      sum8 += c8[i];
    }
    uint32_t incl = sum8;
#pragma unroll
    for (int d = 1; d < 64; d <<= 1) {
      uint32_t v = (uint32_t)__shfl_up((int)incl, d);
      if (lane >= d) incl += v;
    }
    if (lane == 63) s_wsum[wv] = incl;
    __syncthreads();
    uint32_t excl = incl - sum8;
    for (int w = 0; w < wv; ++w) excl += s_wsum[w];
    if ((uint32_t)kk >= excl && (uint32_t)kk < excl + sum8) {
      int k2 = kk - (int)excl;
      int i = 0;
      while (i < 7 && k2 >= (int)c8[i]) {
        k2 -= (int)c8[i];
        ++i;
      }
      s_bin = tid * 8 + i;
      s_kk = k2;
    }
    __syncthreads();
    pref |= ((uint32_t)s_bin) << shift;
    kk = s_kk;
  }
  const float a_lo = __uint_as_float(pref);

  float a_hi_v;
  if (hi_i == lo_i) {
    a_hi_v = a_lo;
  } else {
    if (tid == 0) {
      s_cnt = 0;
      s_minv = 0xFFFFFFFFu;
    }
    __syncthreads();
    int cnt = 0;
    uint32_t mn = 0xFFFFFFFFu;
    for (int r = tid; r < W_LEN; r += 256) {
      uint32_t key = keys[r];
      if (key <= pref)
        cnt++;
      else
        mn = min(mn, key);
    }
    atomicAdd(&s_cnt, cnt);
    atomicMin(&s_minv, mn);
    __syncthreads();
    a_hi_v = (s_cnt >= lo_i + 2) ? a_lo : __uint_as_float(s_minv);
  }

  if (tid == 0)
    thr[row] = __fadd_rn(__fmul_rn(a_lo, lw), __fmul_rn(a_hi_v, gw));
}

// ---------------------------------------------------------------------------
// K3: mask + IDWT + transpose-out. REC_LO[u]=DEC_LO[15-u];
// REC_HI[u]=(u odd?-:+)DEC_LO[u]. All coeff indices in-bounds for T=4096.
// Block: 256 thr, (b, 64-c, 64-s). Register-window stencil: each thread
// loads its 9 distinct (ca,cd) float4s once (was 64 ds_read_b128 with 3.6x
// redundancy; mm = (ss>>1)+7-j for both parities). Nontemporal out stores.
// ---------------------------------------------------------------------------
#define K3_PITCH 68 // float4-aligned LDS pitch

__global__ __launch_bounds__(256) void k_idwt(const float* __restrict__ lo,
                                              const float* __restrict__ hi,
                                              const float* __restrict__ thr,
                                              float* __restrict__ out) {
  __shared__ float s_ca[40 * K3_PITCH];
  __shared__ float s_cd[40 * K3_PITCH];
  __shared__ float s_thr[64];
  const int s0 = blockIdx.x * 64;
  const int bc = blockIdx.y;
  const int b = bc >> 3;
  const int c0 = (bc & 7) * 64;
  const int m0 = s0 >> 1;
  const int tid = threadIdx.x;

  if (tid < 64) s_thr[tid] = thr[b * C_LEN + c0 + tid];
  __syncthreads();

  // stage 40 coeffs x 64 ch; float4 row loads (m0+40 <= 2056 <= pitch: the
  // over-read hits row padding, only mm=39 which is never used in compute)
  for (int r = tid; r < 64 * 10; r += 256) {
    int cc = r / 10;
    int m4 = r % 10;
    size_t base = (size_t)(b * C_LEN + c0 + cc) * W_PITCH + m0 + m4 * 4;
    float4 a = *(const float4*)(lo + base);
    float4 d = *(const float4*)(hi + base);
    float th = s_thr[cc];
    d.x = (__fmul_rn(d.x, d.x) > th) ? d.x : 0.f;
    d.y = (__fmul_rn(d.y, d.y) > th) ? d.y : 0.f;
    d.z = (__fmul_rn(d.z, d.z) > th) ? d.z : 0.f;
    d.w = (__fmul_rn(d.w, d.w) > th) ? d.w : 0.f;
    int li = (m4 * 4) * K3_PITCH + cc;
    s_ca[li] = a.x;
    s_ca[li + K3_PITCH] = a.y;
    s_ca[li + 2 * K3_PITCH] = a.z;
    s_ca[li + 3 * K3_PITCH] = a.w;
    s_cd[li] = d.x;
    s_cd[li + K3_PITCH] = d.y;
    s_cd[li + 2 * K3_PITCH] = d.z;
    s_cd[li + 3 * K3_PITCH] = d.w;
  }
  __syncthreads();

  const int cg = (tid & 15) * 4; // 4 consecutive channels per thread
  const int sb = (tid >> 4) * 4; // 4 consecutive s per thread
  const int a0 = sb >> 1;        // window base: mm in [a0, a0+8]

  // load the 9-float4 window once per array
  float4 A[9], D[9];
#pragma unroll
  for (int m = 0; m < 9; ++m) {
    A[m] = *(const float4*)&s_ca[(a0 + m) * K3_PITCH + cg];
    D[m] = *(const float4*)&s_cd[(a0 + m) * K3_PITCH + cg];
  }

#pragma unroll
  for (int k = 0; k < 4; ++k) {
    const int ss = sb + k;
    const int base = (k >> 1) + 7; // idx = base - j; a = a0 + (k>>1)
    float4 acc = {0.f, 0.f, 0.f, 0.f};
#pragma unroll
    for (int j = 0; j < 8; ++j) {
      const int u = 2 * j + (k & 1); // even ss -> even taps, odd ss -> odd
      const int idx = base - j;      // mm - a0, identical math to (ss+14-u)>>1
      const float rl = c_dec_lo[15 - u];
      const float rh = (u & 1) ? -c_dec_lo[u] : c_dec_lo[u];
      float4 ca = A[idx];
      float4 cd = D[idx];
      acc.x = fmaf(rl, ca.x, acc.x);
      acc.y = fmaf(rl, ca.y, acc.y);
      acc.z = fmaf(rl, ca.z, acc.z);
      acc.w = fmaf(rh, cd.w, fmaf(rl, ca.w, acc.w));
      acc.x = fmaf(rh, cd.x, acc.x);
      acc.y = fmaf(rh, cd.y, acc.y);
      acc.z = fmaf(rh, cd.z, acc.z);
    }
    f32x4 v = {acc.x, acc.y, acc.z, acc.w};
    __builtin_nontemporal_store(
        v, (f32x4*)(out + ((size_t)b * T_LEN + s0 + ss) * C_LEN + c0 + cg));
  }
}

// ---------------------------------------------------------------------------
extern "C" void kernel_launch(void* const* d_in, const int* in_sizes, int n_in,
                              void* d_out, int out_size, void* d_ws,
                              size_t ws_size, hipStream_t stream) {
  const float* x = (const float*)d_in[0];
  const float* qp = (const float*)d_in[1];
  float* out = (float*)d_out;

  // workspace: lo | hi | thr  (~258 MiB)
  float* lo = (float*)d_ws;
  float* hi = lo + (size_t)ROWS * W_PITCH;
  float* thr = hi + (size_t)ROWS * W_PITCH;

  dim3 g1((W_LEN + K1_WT - 1) / K1_WT, 256); // 33 x 256
  k_dwt<<<g1, 256, 0, stream>>>(x, lo, hi);

  k_thresh<<<dim3(ROWS), 256, 0, stream>>>(hi, qp, thr);

  dim3 g3(T_LEN / 64, 256); // 64 x 256
  k_idwt<<<g3, 256, 0, stream>>>(lo, hi, thr, out);
}

// Round 3
// 623.421 us; speedup vs baseline: 1.1211x; 1.1057x over previous
//
#include <hip/hip_runtime.h>
#include <stdint.h>

// Problem constants (fixed by reference: x_in (32, 4096, 512) fp32)
#define T_LEN 4096
#define C_LEN 512
#define B_LEN 32
#define W_LEN 2055 // floor((T + 16 - 1)/2)
#define NCH 16     // channels per block
#define HPITCH 2057 // hi LDS row pitch (2057%32=9 -> conflict-free c-strides)
#define XPITCH 21   // x stage pitch (<=2-way banks for windowed reads)
#define LPITCH 17   // lo stage pitch (<=2-way banks)
#define NCHUNK1 33  // DWT chunks: ceil(2055/64) (last produces 7 w)
#define NCHUNK3 32  // IDWT chunks: 4096/128
#define LO_ROWS 2056 // per-block lo scratch rows (1 pad row for prefetch)

typedef float f32x4 __attribute__((ext_vector_type(4)));

// db8 decomposition low-pass filter (float32-rounded)
__device__ __constant__ float c_dec_lo[16] = {
    (float)-0.00011747678400228192, (float)0.0006754494059985568,
    (float)-0.0003917403729959771,  (float)-0.00487035299301066,
    (float)0.008746094047015655,    (float)0.013981027917015516,
    (float)-0.04408825393106472,    (float)-0.01736930100202211,
    (float)0.128747426620186,       (float)0.00047248457399797254,
    (float)-0.2840155429624281,     (float)-0.015829105256023893,
    (float)0.5853546836548691,      (float)0.6756307362980128,
    (float)0.3128715909144659,      (float)0.05441584224308161};

// Symmetric extension: E[j] -> x index. E = [x14..x0 | x0..x_{T-1} | x_{T-1}..]
__device__ __forceinline__ int sym_idx(int j) {
  int t = j - 15;
  if (t < 0) t = -1 - t;
  if (t >= T_LEN) t = 2 * T_LEN - 1 - t;
  return t;
}

// ---------------------------------------------------------------------------
// Fused kernel: one block per (batch, 16-channel tile). 1024 threads.
//   P1: DWT (33 chunks of 128 t) -> hi rows kept in LDS, lo -> global scratch
//   P2: per-channel quantile, one wave per channel, 4x8-bit radix select
//       (bit-identical keys/selection/interpolation to the 3-pass version);
//       mask applied to hi in-place in LDS
//   P3: IDWT (32 chunks of 128 t) with lo chunks prefetched to registers,
//       coalesced nontemporal out stores
// Eliminates all hi global round-trips (405 MB) and two kernel launches.
// LDS: 131648 (hi) + 16384 (hist) + 11928 (stage) + 64 = 160,024 B.
// ---------------------------------------------------------------------------
__global__ __launch_bounds__(1024) void k_fused(const float* __restrict__ x,
                                                const float* __restrict__ qp,
                                                float* __restrict__ lo_ws,
                                                float* __restrict__ out) {
  __shared__ float hi_lds[NCH * HPITCH];
  __shared__ __align__(16) uint32_t hist[NCH * 256];
  __shared__ float stage[142 * XPITCH]; // P1 x tile; reused as P3 lo tile
  __shared__ float s_thr[NCH];

  // XCD-chunked swizzle: consecutive logical blocks (which share 128B lines
  // of x and neighbor lo scratch) land on the same XCD's L2.
  const int o = blockIdx.x;
  const int blk = (o & 7) * 128 + (o >> 3); // 1024 = 8 * 128, bijective
  const int b = blk >> 5;
  const int c0 = (blk & 31) * NCH;
  const int tid = threadIdx.x;
  float* lo_blk = lo_ws + (size_t)blk * (LO_ROWS * NCH);
  const size_t xrow = (size_t)b * T_LEN;

  const int cth = tid & 15; // channel within tile (P1/P3 compute)
  const int wl = tid >> 4;  // 0..63

  // ---------------- P1: DWT ----------------
  // stage layout: stage[jj*XPITCH + c], jj in [0,142). 2272 elements,
  // slots per thread: tid, tid+1024, tid+2048 (tid<224).
  const int s_jj0 = tid >> 4;
  const int s_jj1 = s_jj0 + 64;  // (tid+1024)>>4
  const int s_jj2 = s_jj0 + 128; // (tid+2048)>>4, valid iff tid<224
  const bool has2 = (tid < 224);

  float pa, pb, pc;
  {
    const int jbase = 1; // chunk 0
    pa = x[(xrow + sym_idx(jbase + s_jj0)) * C_LEN + c0 + cth];
    pb = x[(xrow + sym_idx(jbase + s_jj1)) * C_LEN + c0 + cth];
    if (has2) pc = x[(xrow + sym_idx(jbase + s_jj2)) * C_LEN + c0 + cth];
  }

  for (int ci = 0; ci < NCHUNK1; ++ci) {
    __syncthreads(); // stage free (previous chunk's reads done)
    stage[s_jj0 * XPITCH + cth] = pa;
    stage[s_jj1 * XPITCH + cth] = pb;
    if (has2) stage[s_jj2 * XPITCH + cth] = pc;
    __syncthreads(); // stage visible
    if (ci + 1 < NCHUNK1) { // prefetch next chunk; lands during compute
      const int jbase = 128 * (ci + 1) + 1;
      pa = x[(xrow + sym_idx(jbase + s_jj0)) * C_LEN + c0 + cth];
      pb = x[(xrow + sym_idx(jbase + s_jj1)) * C_LEN + c0 + cth];
      if (has2) pc = x[(xrow + sym_idx(jbase + s_jj2)) * C_LEN + c0 + cth];
    }
    const int w = 64 * ci + wl;
    if (w < W_LEN) {
      float accl = 0.f, acch = 0.f;
#pragma unroll
      for (int u = 0; u < 16; ++u) {
        float e = stage[(2 * wl + 15 - u) * XPITCH + cth];
        accl = fmaf(c_dec_lo[u], e, accl);
        float dh = (u & 1) ? c_dec_lo[15 - u] : -c_dec_lo[15 - u];
        acch = fmaf(dh, e, acch);
      }
      hi_lds[cth * HPITCH + w] = acch;
      lo_blk[w * NCH + cth] = accl; // cached store (read back in P3)
    }
  }
  __syncthreads(); // all hi rows complete in LDS

  // ---------------- P2: quantile, one wave per channel ----------------
  const float q = qp[0];
  float pos = __fmul_rn(q, (float)(W_LEN - 1));
  if (pos < 0.f) pos = 0.f;
  if (pos > (float)(W_LEN - 1)) pos = (float)(W_LEN - 1);
  const int lo_i = (int)floorf(pos);
  const int hi_i = (int)ceilf(pos);
  const float gwt = pos - floorf(pos);
  const float lwt = 1.0f - gwt;

  const int ch = tid >> 6; // wave id = channel
  const int ln = tid & 63;
  uint32_t* hh = hist + ch * 256;
  const float* hrow = hi_lds + ch * HPITCH;

  int kk = lo_i;
  uint32_t pref = 0;
  const uint32_t pmask[4] = {0u, 0xFF000000u, 0xFFFF0000u, 0xFFFFFF00u};
#pragma unroll
  for (int p = 0; p < 4; ++p) {
    const int shift = 24 - 8 * p;
    {
      uint4 z = {0u, 0u, 0u, 0u};
      *(uint4*)(hh + 4 * ln) = z; // zero own 4 bins (16B aligned)
    }
    __syncthreads();
    for (int i = ln; i < W_LEN; i += 64) {
      float v = hrow[i];
      uint32_t key = __float_as_uint(__fmul_rn(v, v));
      if ((key & pmask[p]) == (pref & pmask[p]))
        atomicAdd(&hh[(key >> shift) & 255u], 1u);
    }
    __syncthreads();
    uint4 cc = *(const uint4*)(hh + 4 * ln);
    const uint32_t sum4 = cc.x + cc.y + cc.z + cc.w;
    uint32_t incl = sum4;
#pragma unroll
    for (int d = 1; d < 64; d <<= 1) {
      uint32_t v = (uint32_t)__shfl_up((int)incl, d);
      if (ln >= d) incl += v;
    }
    const uint32_t excl = incl - sum4;
    const bool has = ((uint32_t)kk >= excl) && ((uint32_t)kk < excl + sum4);
    int k2 = kk - (int)excl;
    int bsel = 0;
    if (has) { // in-range lane locates its bin (static unrolled search)
      if (k2 >= (int)cc.x) {
        k2 -= (int)cc.x;
        bsel = 1;
        if (k2 >= (int)cc.y) {
          k2 -= (int)cc.y;
          bsel = 2;
          if (k2 >= (int)cc.z) {
            k2 -= (int)cc.z;
            bsel = 3;
          }
        }
      }
    }
    const unsigned long long mvote = __ballot(has ? 1 : 0);
    const int src = __ffsll(mvote) - 1; // guaranteed nonzero vote
    const int binv = __shfl(4 * ln + bsel, src);
    kk = __shfl(k2, src);
    pref |= ((uint32_t)binv) << shift;
    __syncthreads();
  }
  const float a_lo = __uint_as_float(pref);

  float a_hi_v;
  if (hi_i == lo_i) {
    a_hi_v = a_lo;
  } else { // need next order statistic: count <= a_lo, min of keys > a_lo
    int cnt = 0;
    uint32_t mn = 0xFFFFFFFFu;
    for (int i = ln; i < W_LEN; i += 64) {
      float v = hrow[i];
      uint32_t key = __float_as_uint(__fmul_rn(v, v));
      if (key <= pref)
        cnt++;
      else
        mn = mn < key ? mn : key;
    }
#pragma unroll
    for (int d = 1; d < 64; d <<= 1) {
      cnt += __shfl_xor(cnt, d);
      uint32_t om = (uint32_t)__shfl_xor((int)mn, d);
      mn = mn < om ? mn : om;
    }
    a_hi_v = (cnt >= lo_i + 2) ? a_lo : __uint_as_float(mn);
  }
  if (ln == 0)
    s_thr[ch] = __fadd_rn(__fmul_rn(a_lo, lwt), __fmul_rn(a_hi_v, gwt));
  __syncthreads();

  // mask hi in place (same __fmul_rn square as the keys -> identical bits)
  for (int cc2 = 0; cc2 < NCH; ++cc2) {
    const float th = s_thr[cc2];
    for (int i = tid; i < W_LEN; i += 1024) {
      float v = hi_lds[cc2 * HPITCH + i];
      hi_lds[cc2 * HPITCH + i] = (__fmul_rn(v, v) > th) ? v : 0.f;
    }
  }
  __syncthreads();

  // ---------------- P3: IDWT + transpose-out ----------------
  // chunk cs: s in [128cs, 128cs+127]; lo rows m in [64cs, 64cs+70]
  // (stage 72 rows as 288 float4s; row 64cs+71 staged but never read)
  const bool ldr = (tid < 288);
  const int g = tid >> 4; // 0..63; outputs s_l = 2g, 2g+1
  f32x4 pf;
  if (ldr) pf = *(const f32x4*)(lo_blk + (size_t)tid * 4); // chunk 0

  for (int cs = 0; cs < NCHUNK3; ++cs) {
    __syncthreads(); // stage free
    if (ldr) {
      const int wloc = tid >> 2;        // 0..71
      const int cc4 = (tid & 3) * 4;    // 0,4,8,12
      const int bse = wloc * LPITCH + cc4;
      stage[bse + 0] = pf.x;
      stage[bse + 1] = pf.y;
      stage[bse + 2] = pf.z;
      stage[bse + 3] = pf.w;
    }
    __syncthreads(); // stage visible
    if (ldr && cs + 1 < NCHUNK3)
      pf = *(const f32x4*)(lo_blk + (size_t)(cs + 1) * 1024 + (size_t)tid * 4);

    float acc0 = 0.f, acc1 = 0.f;
    const int mg = 64 * cs;
#pragma unroll
    for (int j = 0; j < 8; ++j) {
      const int ml = g + 7 - j; // mm - 64cs, identical math to (s+14-u)>>1
      const float ca = stage[ml * LPITCH + cth];
      const float cd = hi_lds[cth * HPITCH + mg + ml];
      const int u0 = 2 * j; // even s: even taps; rh=+dec_lo[u0]
      acc0 = fmaf(c_dec_lo[u0], cd, fmaf(c_dec_lo[15 - u0], ca, acc0));
      const int u1 = 2 * j + 1; // odd s: odd taps; rh=-dec_lo[u1]
      acc1 = fmaf(-c_dec_lo[u1], cd, fmaf(c_dec_lo[15 - u1], ca, acc1));
    }
    const size_t ob = (xrow + 128 * cs + 2 * g) * C_LEN + c0 + cth;
    __builtin_nontemporal_store(acc0, out + ob);
    __builtin_nontemporal_store(acc1, out + ob + C_LEN);
  }
}

// ---------------------------------------------------------------------------
extern "C" void kernel_launch(void* const* d_in, const int* in_sizes, int n_in,
                              void* d_out, int out_size, void* d_ws,
                              size_t ws_size, hipStream_t stream) {
  const float* x = (const float*)d_in[0];
  const float* qp = (const float*)d_in[1];
  float* out = (float*)d_out;
  float* lo_ws = (float*)d_ws; // 1024 * 2056 * 16 * 4 B = 134.7 MB

  k_fused<<<dim3(B_LEN * (C_LEN / NCH)), dim3(1024), 0, stream>>>(x, qp, lo_ws,
                                                                  out);
}

// Round 4
// 553.492 us; speedup vs baseline: 1.2627x; 1.1263x over previous
//
#include <hip/hip_runtime.h>
#include <stdint.h>

// Problem constants (fixed by reference: x_in (32, 4096, 512) fp32)
#define T_LEN 4096
#define C_LEN 512
#define B_LEN 32
#define W_LEN 2055  // floor((T + 16 - 1)/2)
#define NCH 16      // channels per block
#define HPITCH 2057 // odd pitch: cth*HPITCH full-rank mod 32 -> uniform 2-way
#define LO_ROWS 2056

// db8 decomposition low-pass filter (float32-rounded)
__device__ __constant__ float c_dec_lo[16] = {
    (float)-0.00011747678400228192, (float)0.0006754494059985568,
    (float)-0.0003917403729959771,  (float)-0.00487035299301066,
    (float)0.008746094047015655,    (float)0.013981027917015516,
    (float)-0.04408825393106472,    (float)-0.01736930100202211,
    (float)0.128747426620186,       (float)0.00047248457399797254,
    (float)-0.2840155429624281,     (float)-0.015829105256023893,
    (float)0.5853546836548691,      (float)0.6756307362980128,
    (float)0.3128715909144659,      (float)0.05441584224308161};

// Symmetric extension: E[j] -> x index. E = [x14..x0 | x0..x_{T-1} | x_{T-1}..]
__device__ __forceinline__ int sym_idx(int j) {
  int t = j - 15;
  if (t < 0) t = -1 - t;
  if (t >= T_LEN) t = 2 * T_LEN - 1 - t;
  return t;
}

// ---------------------------------------------------------------------------
// Fused kernel v2: one block per (batch, 16-channel tile). 1024 threads.
// LDS-minimal design (v1 was LDS-pipe-bound: ~2000 LDS instr/wave, 135
// barriers, 49M conflict cycles):
//   P1: stage-free DWT. Thread (cth,wl) computes 8 consecutive w via a
//       30-float register window loaded straight from global (L1 absorbs the
//       2.75x halo re-read; 16 cth-lanes = 64B segments). hi -> LDS rows,
//       lo -> block-private global scratch [m][16c]. No barriers.
//   P2: per-channel quantile, one wave per channel, 33 keys held in VGPRs
//       (static indexing). 4x8-bit radix select with digits cut at the
//       exponent byte [30:23] (spreads the atomic histogram ~3x vs sign+7exp)
//       then [22:15],[14:7],[7:0]. Wave-private hist -> no barriers.
//       Mask applied from register keys (stores only zeros).
//   P3: stage-free IDWT. 8 outputs/thread; lo window (11) read from global
//       (64B rows, L2/L3-resident), hi window (11) from LDS (2-way banks).
// Barriers: 2 total. LDS: 131,648 (hi) + 16,384 (hist) = 148 KB.
// ---------------------------------------------------------------------------
__global__ __launch_bounds__(1024) void k_fused(const float* __restrict__ x,
                                                const float* __restrict__ qp,
                                                float* __restrict__ lo_ws,
                                                float* __restrict__ out) {
  __shared__ float hi_lds[NCH * HPITCH];
  __shared__ __align__(16) uint32_t hist[NCH * 256];

  // XCD-chunked swizzle: adjacent c-tiles (which share 128B x/out lines)
  // land on the same XCD close in time.
  const int o = blockIdx.x;
  const int blk = (o & 7) * 128 + (o >> 3); // 1024 = 8*128, bijective
  const int b = blk >> 5;
  const int c0 = (blk & 31) * NCH;
  const int tid = threadIdx.x;
  float* lo_blk = lo_ws + (size_t)blk * (LO_ROWS * NCH);
  const size_t xrow = (size_t)b * T_LEN;

  const int cth = tid & 15;
  const int wl = tid >> 4; // 0..63

  // ---------------- P1: DWT (no LDS staging, no barriers) ----------------
  const float* xc = x + xrow * C_LEN + c0 + cth;
#pragma unroll
  for (int m = 0; m < 4; ++m) {
    const int wb = 8 * wl + 512 * m; // 8 consecutive w per thread
    float E[30];                     // t = 2wb-14 .. 2wb+15
    if (wb == 0) {                   // only wl==0,m==0 reflects
#pragma unroll
      for (int i = 0; i < 30; ++i) E[i] = xc[(size_t)sym_idx(1 + i) * C_LEN];
    } else {
      const float* p = xc + (size_t)(2 * wb - 14) * C_LEN;
#pragma unroll
      for (int i = 0; i < 30; ++i) E[i] = p[(size_t)i * C_LEN];
    }
#pragma unroll
    for (int k = 0; k < 8; ++k) {
      float accl = 0.f, acch = 0.f;
#pragma unroll
      for (int u = 0; u < 16; ++u) {
        float e = E[2 * k + 15 - u]; // t = 2(wb+k)+1-u
        accl = fmaf(c_dec_lo[u], e, accl);
        float dh = (u & 1) ? c_dec_lo[15 - u] : -c_dec_lo[15 - u];
        acch = fmaf(dh, e, acch);
      }
      hi_lds[cth * HPITCH + wb + k] = acch;
      lo_blk[(wb + k) * NCH + cth] = accl;
    }
  }
  if (wl < 7) { // tail w = 2048..2054
    const int w = 2048 + wl;
    float accl = 0.f, acch = 0.f;
#pragma unroll
    for (int u = 0; u < 16; ++u) {
      float e = xc[(size_t)sym_idx(2 * w + 16 - u) * C_LEN];
      accl = fmaf(c_dec_lo[u], e, accl);
      float dh = (u & 1) ? c_dec_lo[15 - u] : -c_dec_lo[15 - u];
      acch = fmaf(dh, e, acch);
    }
    hi_lds[cth * HPITCH + w] = acch;
    lo_blk[w * NCH + cth] = accl;
  }
  __syncthreads(); // hi rows complete

  // ---------------- P2: quantile, one wave per channel, no barriers -------
  const float q = qp[0];
  float pos = __fmul_rn(q, (float)(W_LEN - 1));
  if (pos < 0.f) pos = 0.f;
  if (pos > (float)(W_LEN - 1)) pos = (float)(W_LEN - 1);
  const int lo_i = (int)floorf(pos);
  const int hi_i = (int)ceilf(pos);
  const float gwt = pos - floorf(pos);
  const float lwt = 1.0f - gwt;

  const int ch = tid >> 6; // wave id = channel
  const int ln = tid & 63;
  const float* hrow = hi_lds + ch * HPITCH;
  uint32_t* hh = hist + ch * 256;

  uint32_t key[33]; // lane ln owns i = ln + 64m (m<32), + 2048+ln if ln<7
#pragma unroll
  for (int m = 0; m < 32; ++m) {
    float v = hrow[ln + 64 * m];
    key[m] = __float_as_uint(__fmul_rn(v, v));
  }
  if (ln < 7) {
    float v = hrow[2048 + ln];
    key[32] = __float_as_uint(__fmul_rn(v, v));
  } else {
    key[32] = 0xFFFFFFFFu; // sentinel: bit31=1 never matches any real prefix
  }

  int kk = lo_i;
  uint32_t pref = 0;
  const int shs[4] = {23, 15, 7, 0};
#pragma unroll
  for (int p = 0; p < 4; ++p) {
    const int sh = shs[p];
    { // zero own 4 bins (wave-private -> no barrier)
      uint4 z = {0u, 0u, 0u, 0u};
      *(uint4*)(hh + 4 * ln) = z;
    }
    const uint32_t pc = pref >> (sh + 8); // p==0: key>>31==0 always matches
#pragma unroll
    for (int m = 0; m < 33; ++m) { // sentinel self-excludes (bit31)
      if ((key[m] >> (sh + 8)) == pc)
        atomicAdd(&hh[(key[m] >> sh) & 255u], 1u);
    }
    uint4 cc = *(const uint4*)(hh + 4 * ln);
    const uint32_t sum4 = cc.x + cc.y + cc.z + cc.w;
    uint32_t incl = sum4;
#pragma unroll
    for (int d = 1; d < 64; d <<= 1) {
      uint32_t v = (uint32_t)__shfl_up((int)incl, d);
      if (ln >= d) incl += v;
    }
    const uint32_t excl = incl - sum4;
    const bool has = ((uint32_t)kk >= excl) && ((uint32_t)kk < excl + sum4);
    int k2 = kk - (int)excl;
    int bsel = 0;
    if (has) {
      if (k2 >= (int)cc.x) {
        k2 -= (int)cc.x;
        bsel = 1;
        if (k2 >= (int)cc.y) {
          k2 -= (int)cc.y;
          bsel = 2;
          if (k2 >= (int)cc.z) {
            k2 -= (int)cc.z;
            bsel = 3;
          }
        }
      }
    }
    const unsigned long long mv = __ballot(has ? 1 : 0);
    const int src = __ffsll(mv) - 1;
    const int binv = __shfl(4 * ln + bsel, src);
    kk = __shfl(k2, src);
    pref |= ((uint32_t)binv) << sh;
  }
  const float a_lo = __uint_as_float(pref);

  float a_hi_v;
  if (hi_i == lo_i) {
    a_hi_v = a_lo;
  } else { // count <= a_lo; min of keys > a_lo (register keys)
    int cnt = 0;
    uint32_t mn = 0xFFFFFFFFu;
#pragma unroll
    for (int m = 0; m < 33; ++m) {
      bool valid = (m < 32) || (ln < 7);
      if (valid) {
        if (key[m] <= pref)
          cnt++;
        else
          mn = mn < key[m] ? mn : key[m];
      }
    }
#pragma unroll
    for (int d = 1; d < 64; d <<= 1) {
      cnt += __shfl_xor(cnt, d);
      uint32_t om = (uint32_t)__shfl_xor((int)mn, d);
      mn = mn < om ? mn : om;
    }
    a_hi_v = (cnt >= lo_i + 2) ? a_lo : __uint_as_float(mn);
  }
  const float th = __fadd_rn(__fmul_rn(a_lo, lwt), __fmul_rn(a_hi_v, gwt));

  // mask own channel from register keys (write only zeros)
#pragma unroll
  for (int m = 0; m < 32; ++m) {
    if (!(__uint_as_float(key[m]) > th)) hi_lds[ch * HPITCH + ln + 64 * m] = 0.f;
  }
  if (ln < 7) {
    if (!(__uint_as_float(key[32]) > th)) hi_lds[ch * HPITCH + 2048 + ln] = 0.f;
  }
  __syncthreads(); // all channels masked

  // ---------------- P3: IDWT + transpose-out (stage-free) -----------------
#pragma unroll
  for (int m2 = 0; m2 < 8; ++m2) {
    const int sg = wl + 64 * m2; // 0..511; outputs ss = 8sg..8sg+7
    const int mb = 4 * sg;       // coeff window mm in [mb, mb+10]
    float A[11], D[11];
#pragma unroll
    for (int i = 0; i < 11; ++i) A[i] = lo_blk[(mb + i) * NCH + cth];
#pragma unroll
    for (int i = 0; i < 11; ++i) D[i] = hi_lds[cth * HPITCH + mb + i];
    const size_t ob = (xrow + 8 * sg) * C_LEN + c0 + cth;
#pragma unroll
    for (int k = 0; k < 8; ++k) {
      // ss = 8sg+k; li = (k>>1)+7-j; u = 2j + (k&1)
      float acc = 0.f;
      const int q2 = k >> 1;
      if ((k & 1) == 0) {
#pragma unroll
        for (int j = 0; j < 8; ++j) {
          const int u = 2 * j;
          const int li = q2 + 7 - j;
          acc = fmaf(c_dec_lo[u], D[li], fmaf(c_dec_lo[15 - u], A[li], acc));
        }
      } else {
#pragma unroll
        for (int j = 0; j < 8; ++j) {
          const int u = 2 * j + 1;
          const int li = q2 + 7 - j;
          acc = fmaf(-c_dec_lo[u], D[li], fmaf(c_dec_lo[15 - u], A[li], acc));
        }
      }
      __builtin_nontemporal_store(acc, out + ob + (size_t)k * C_LEN);
    }
  }
}

// ---------------------------------------------------------------------------
extern "C" void kernel_launch(void* const* d_in, const int* in_sizes, int n_in,
                              void* d_out, int out_size, void* d_ws,
                              size_t ws_size, hipStream_t stream) {
  const float* x = (const float*)d_in[0];
  const float* qp = (const float*)d_in[1];
  float* out = (float*)d_out;
  float* lo_ws = (float*)d_ws; // 1024 * 2056 * 16 * 4 B = 134.7 MB

  k_fused<<<dim3(B_LEN * (C_LEN / NCH)), dim3(1024), 0, stream>>>(x, qp, lo_ws,
                                                                  out);
}